// Round 19
// baseline (237.954 us; speedup 1.0000x reference)
//
#include <hip/hip_runtime.h>
#include <math.h>
#include <string.h>

#define W 1024
#define H 1024
#define HW (1024*1024)
#define NP 24                 // B*C planes

typedef float  f32x4  __attribute__((ext_vector_type(4)));
typedef short  bf16x8 __attribute__((ext_vector_type(8)));

struct Weights { float w[273]; };   // w80[161]@0, w40[81]@161, w15[31]@242

// LDS pitches (shorts), ≡8 mod 64. Ledger: r11 tile-shrink, r13 de-staging, r16
// persistence all regressed; r17 occupancy null; r18 barrier-removal null (and L3-
// served replays run same speed -> not memory-bound). r19: k-outer conv reorder
// (break per-acc MFMA dependency chains; accumulation order per acc unchanged).
#define P1PIT 456
#define P2P80 328
#define P2P40 264
#define P2P15 200

#define NSLOT 64              // min/max atomic buckets

// planesT blocked layout: elem(sp, y, x) at sp*HW + (y>>5)*32768 + x*32 + (y&31)

// ---------- helpers ----------

__device__ __forceinline__ unsigned fenc(float f) {
  unsigned u = __float_as_uint(f);
  return (u & 0x80000000u) ? ~u : (u | 0x80000000u);
}
__device__ __forceinline__ float fdec(unsigned e) {
  unsigned u = (e & 0x80000000u) ? (e & 0x7fffffffu) : ~e;
  return __uint_as_float(u);
}
__device__ __forceinline__ unsigned bfbits(float f) {   // f32 -> bf16 bits, RNE
  unsigned u = __float_as_uint(f);
  return (u + 0x7fffu + ((u >> 16) & 1u)) >> 16;
}

__device__ __forceinline__ void minmax_reduce4(float lmn, float lmx, unsigned* mm,
                                               float* red, int slot) {
  #pragma unroll
  for (int off = 32; off > 0; off >>= 1) {
    lmn = fminf(lmn, __shfl_xor(lmn, off));
    lmx = fmaxf(lmx, __shfl_xor(lmx, off));
  }
  const int tid = threadIdx.x;
  const int wid = tid >> 6;
  if ((tid & 63) == 0) { red[wid] = lmn; red[4 + wid] = lmx; }
  __syncthreads();
  if (tid == 0) {
    float mn = fminf(fminf(red[0], red[1]), fminf(red[2], red[3]));
    float mx = fmaxf(fmaxf(red[4], red[5]), fmaxf(red[6], red[7]));
    atomicMin(mm + 2 * slot, fenc(mn));
    atomicMax(mm + 2 * slot + 1, fenc(mx));
  }
}

// ---------- init: Toeplitz B-fragment table [3][6][64 lanes] x 8 bf16 ----------

__global__ void msr_fraginit(Weights wt, ushort* __restrict__ frag, unsigned* __restrict__ mm) {
  const int tid = threadIdx.x;
  if (tid < NSLOT) { mm[2 * tid] = 0xFFFFFFFFu; mm[2 * tid + 1] = 0u; }
  const int pads[3] = {80, 40, 15};
  const int woff[3] = {0, 161, 242};
  const int t0s[3]  = {11, 13, 15};
  for (int e = tid; e < 3 * 6 * 64; e += 256) {
    const int s = e / 384;
    const int rem = e - s * 384;
    const int k = rem >> 6;
    const int lane = rem & 63;
    const int pad = pads[s];
    const int d = pad + (t0s[s] + 2 * k) * 16 - 256;
    ushort* dst = frag + e * 8;
    for (int j = 0; j < 8; ++j) {
      const int kk = ((lane >> 4) << 3) + j;
      const int c  = lane & 15;
      const int idx = d + kk - c;
      float v = (idx >= 0 && idx <= 2 * pad) ? wt.w[woff[s] + idx] : 0.f;
      dst[j] = (ushort)bfbits(v);
    }
  }
}

// ---------- pass 1: horizontal blur, 256-wide x-tiles; k-outer conv; no barrier ----------
// Staging is wave-private (tid 0..63 -> rows 0..15 = wave 0's conv read set), so the
// block barrier is unnecessary; same-wave ordering via lgkmcnt.

template<int NK, int C0, int FB>
__device__ __forceinline__ void h_round(const short* __restrict__ lds,
                                        const bf16x8* __restrict__ fragv,
                                        ushort* __restrict__ pT,
                                        int lane, int rowshort, int x16, int yin) {
  bf16x8 fr[NK];
  #pragma unroll
  for (int k = 0; k < NK; ++k) fr[k] = fragv[(FB + k) * 64 + lane];
  f32x4 acc[16];
  #pragma unroll
  for (int tx = 0; tx < 16; ++tx) acc[tx] = (f32x4){0.f, 0.f, 0.f, 0.f};
  #pragma unroll
  for (int k = 0; k < NK; ++k) {          // k OUTER: 16 independent MFMA chains
    #pragma unroll
    for (int tx = 0; tx < 16; ++tx) {
      bf16x8 a = *(const bf16x8*)(lds + rowshort + tx * 16 + C0 + 32 * k);
      acc[tx] = __builtin_amdgcn_mfma_f32_16x16x32_bf16(a, fr[k], acc[tx], 0, 0, 0);
    }
  }
  #pragma unroll
  for (int tx = 0; tx < 16; ++tx) {
    const unsigned lo = bfbits(acc[tx][0]) | (bfbits(acc[tx][1]) << 16);
    const unsigned hi = bfbits(acc[tx][2]) | (bfbits(acc[tx][3]) << 16);
    *(uint2*)(pT + (size_t)(x16 + tx * 16) * 32 + yin) = make_uint2(lo, hi);
  }
}

__global__ __launch_bounds__(128, 2) void msr_hblur3(
    const float* __restrict__ img, ushort* __restrict__ planesT,
    const bf16x8* __restrict__ fragv) {
  __shared__ __align__(16) short lds[32 * P1PIT];   // 29184 B
  const int tid = threadIdx.x;
  const int orig = blockIdx.x + (blockIdx.y << 2) + (blockIdx.z << 7);
  const int l = (orig & 7) * 384 + (orig >> 3);     // bijective (3072 = 8*384)
  const int bx = l & 3;            // x-tile (256 wide, halo axis)
  const int by = (l >> 2) & 31;    // y-strip (32 tall)
  const int bp = l >> 7;           // plane
  const int x0 = bx * 256, y0 = by * 32;
  const float* sp = img + (size_t)bp * HW;
  const int row = tid >> 2, c4 = tid & 3;
  const bool interior = (bx == 1 || bx == 2);
  #pragma unroll
  for (int it = 0; it < 28; ++it) {
    const int ccpx = 4 * c4 + 16 * it;
    const int gx0 = x0 - 96 + ccpx;
    unsigned lo, hi;
    if (interior || (gx0 >= 0 && gx0 + 4 <= W)) {
      const float4 v = *(const float4*)(sp + (size_t)(y0 + row) * W + gx0);
      lo = bfbits(v.x) | (bfbits(v.y) << 16);
      hi = bfbits(v.z) | (bfbits(v.w) << 16);
    } else {
      unsigned us[4];
      #pragma unroll
      for (int j = 0; j < 4; ++j) {
        int gx = gx0 + j;
        gx = gx < 0 ? -gx : (gx >= W ? 2 * W - 2 - gx : gx);
        us[j] = bfbits(sp[(size_t)(y0 + row) * W + gx]);
      }
      lo = us[0] | (us[1] << 16); hi = us[2] | (us[3] << 16);
    }
    *(uint2*)(lds + row * P1PIT + ccpx) = make_uint2(lo, hi);
  }
  // no __syncthreads: staging rows (tid>>2) are wave-private to the conv read set

  const int lane = tid & 63;
  const int wrow = (tid >> 6) * 16;
  const int q = lane >> 4;
  const int rowshort = (wrow + (lane & 15)) * P1PIT + q * 8;
  const int x16 = x0 + (lane & 15);
  const int yin = wrow + q * 4;
  const size_t sb = (size_t)by * 32768;

  h_round<6, 16, 0>(lds, fragv, planesT + (size_t)(0 * NP + bp) * HW + sb, lane, rowshort, x16, yin);
  h_round<4, 48, 6>(lds, fragv, planesT + (size_t)(1 * NP + bp) * HW + sb, lane, rowshort, x16, yin);
  h_round<2, 80, 12>(lds, fragv, planesT + (size_t)(2 * NP + bp) * HW + sb, lane, rowshort, x16, yin);
}

// ---------- pass 2: wave-private staging (r18), k-outer conv, product-log, bf16 ret ----

template<int NCH, int WD>
__device__ __forceinline__ void p2_prefetch(const ushort* __restrict__ pTs, int xrow,
                                            int ystart, int c4, uint4 (&pre)[10]) {
  #pragma unroll
  for (int i = 0; i < NCH; ++i) {
    const int ccpx = 8 * c4 + 32 * i;
    if (ccpx < WD) {
      const int gy = ystart + ccpx;                // ≡0 mod 8 -> never straddles a strip
      if (gy >= 0 && gy + 8 <= H) {
        pre[i] = *(const uint4*)(pTs + (size_t)(gy >> 5) * 32768 + (size_t)xrow * 32 + (gy & 31));
      } else {
        union { ushort u[8]; uint4 v; } t;
        #pragma unroll
        for (int j = 0; j < 8; ++j) {
          int g = gy + j;
          g = g < 0 ? -g : (g >= H ? 2 * H - 2 - g : g);
          t.u[j] = pTs[(size_t)(g >> 5) * 32768 + (size_t)xrow * 32 + (g & 31)];
        }
        pre[i] = t.v;
      }
    }
  }
}

template<int NCH, int WD, int PIT>
__device__ __forceinline__ void p2_wlds(short* __restrict__ lds, int srow, int c4,
                                        const uint4 (&pre)[10]) {
  #pragma unroll
  for (int i = 0; i < NCH; ++i) {
    const int ccpx = 8 * c4 + 32 * i;
    if (ccpx < WD) *(uint4*)(lds + srow * PIT + ccpx) = pre[i];
  }
}

template<int NK, int PIT, int FB, bool FIRST>
__device__ __forceinline__ void p2_convprod(const short* __restrict__ lds,
                                            const bf16x8* __restrict__ fragv,
                                            int lane, int wrow, float* prod) {
  const int rowshort = (wrow + (lane & 15)) * PIT + (lane >> 4) * 8;
  bf16x8 fr[NK];
  #pragma unroll
  for (int k = 0; k < NK; ++k) fr[k] = fragv[(FB + k) * 64 + lane];
  f32x4 acc[8];
  #pragma unroll
  for (int tx = 0; tx < 8; ++tx) acc[tx] = (f32x4){0.f, 0.f, 0.f, 0.f};
  #pragma unroll
  for (int k = 0; k < NK; ++k) {          // k OUTER: 8 independent MFMA chains
    #pragma unroll
    for (int tx = 0; tx < 8; ++tx) {
      bf16x8 a = *(const bf16x8*)(lds + rowshort + tx * 16 + 32 * k);
      acc[tx] = __builtin_amdgcn_mfma_f32_16x16x32_bf16(a, fr[k], acc[tx], 0, 0, 0);
    }
  }
  #pragma unroll
  for (int tx = 0; tx < 8; ++tx) {
    #pragma unroll
    for (int r = 0; r < 4; ++r) {
      const float v = acc[tx][r] + 2e-6f;
      if (FIRST) prod[tx * 4 + r] = v;
      else       prod[tx * 4 + r] *= v;
    }
  }
}

__global__ __launch_bounds__(256) __attribute__((amdgpu_waves_per_eu(2, 3)))
void msr_vblur3(
    const ushort* __restrict__ planesT, const float* __restrict__ img,
    ushort* __restrict__ ret, const bf16x8* __restrict__ fragv, unsigned* __restrict__ mm) {
  __shared__ __align__(16) short lds[64 * P2P80];   // 41984 B
  __shared__ float red[8];
  const int tid = threadIdx.x;
  const int orig = blockIdx.x + (blockIdx.y << 4) + (blockIdx.z << 7);
  const int l = (orig & 7) * 384 + (orig >> 3);     // bijective (3072 = 8*384)
  const int byt = l & 7;           // y-tile (128 tall, halo axis -> same XCD)
  const int bxt = (l >> 3) & 15;   // x-tile (64 wide)
  const int bp = l >> 7;
  const int x0 = bxt * 64, y0 = byt * 128;
  const int lane = tid & 63;
  const int wrow = (tid >> 6) * 16;
  const int srow = wrow + (lane >> 2);    // wave-private staging row (16 per wave)
  const int c4 = lane & 3;
  const int q = lane >> 4;
  const int xb = x0 + wrow + 4 * q;       // C rows = x (4 consecutive per lane)
  const int ycb = y0 + (lane & 15);       // C cols = y (+ tx*16)

  const ushort* pT0 = planesT + (size_t)(0 * NP + bp) * HW;
  const ushort* pT1 = planesT + (size_t)(1 * NP + bp) * HW;
  const ushort* pT2 = planesT + (size_t)(2 * NP + bp) * HW;

  uint4 pre[10];
  p2_prefetch<10, 304>(pT0, x0 + srow, y0 - 80, c4, pre);  // sigma80 window in flight

  // accL init from img (VALU stretch overlaps prefetch)
  float accL[32];
  const float* ip = img + (size_t)bp * HW;
  #pragma unroll
  for (int tx = 0; tx < 8; ++tx) {
    const float4 v = *(const float4*)(ip + (size_t)(ycb + tx * 16) * W + xb);
    accL[tx * 4 + 0] = 3.f * __logf(v.x + 1e-6f);
    accL[tx * 4 + 1] = 3.f * __logf(v.y + 1e-6f);
    accL[tx * 4 + 2] = 3.f * __logf(v.z + 1e-6f);
    accL[tx * 4 + 3] = 3.f * __logf(v.w + 1e-6f);
  }

  float prod[32];
  // round sigma80 (no barriers: wave-private stripes)
  p2_wlds<10, 304, P2P80>(lds, srow, c4, pre);
  p2_prefetch<8, 240>(pT1, x0 + srow, y0 - 48, c4, pre);   // next round in flight
  p2_convprod<6, P2P80, 0, true>(lds, fragv, lane, wrow, prod);
  // round sigma40
  p2_wlds<8, 240, P2P40>(lds, srow, c4, pre);
  p2_prefetch<6, 176>(pT2, x0 + srow, y0 - 16, c4, pre);
  p2_convprod<4, P2P40, 6, false>(lds, fragv, lane, wrow, prod);
  // round sigma15
  p2_wlds<6, 176, P2P15>(lds, srow, c4, pre);
  p2_convprod<2, P2P15, 12, false>(lds, fragv, lane, wrow, prod);

  ushort* rp = ret + (size_t)bp * HW;
  float lmn = 3.4e38f, lmx = -3.4e38f;
  #pragma unroll
  for (int tx = 0; tx < 8; ++tx) {
    #pragma unroll
    for (int r = 0; r < 4; ++r) {
      accL[tx * 4 + r] -= __logf(prod[tx * 4 + r]);
      lmn = fminf(lmn, accL[tx * 4 + r]);
      lmx = fmaxf(lmx, accL[tx * 4 + r]);
    }
    const unsigned lo = bfbits(accL[tx * 4 + 0]) | (bfbits(accL[tx * 4 + 1]) << 16);
    const unsigned hi = bfbits(accL[tx * 4 + 2]) | (bfbits(accL[tx * 4 + 3]) << 16);
    *(uint2*)(rp + (size_t)(ycb + tx * 16) * W + xb) = make_uint2(lo, hi);
  }
  minmax_reduce4(lmn, lmx, mm, red, orig & (NSLOT - 1));
}

// ---------- normalize: self-reduces slots; reads bf16 retinex, writes f32 out ----------

__global__ __launch_bounds__(256) void msr_norm(const ushort* __restrict__ ret,
                                                float* __restrict__ out,
                                                const unsigned* __restrict__ mm) {
  __shared__ float smn, ssc;
  const int tid = threadIdx.x;
  if (tid < 64) {
    unsigned e = mm[2 * tid];
    unsigned f = mm[2 * tid + 1];
    #pragma unroll
    for (int off = 32; off > 0; off >>= 1) {
      unsigned eo = (unsigned)__shfl_xor((int)e, off);
      unsigned fo = (unsigned)__shfl_xor((int)f, off);
      e = eo < e ? eo : e;
      f = fo > f ? fo : f;
    }
    if (tid == 0) {
      const float mn = fdec(e), mx = fdec(f);
      smn = mn;
      ssc = 255.f / (mx - mn);
    }
  }
  __syncthreads();
  const float mn = smn, sc = ssc;
  const size_t i = ((size_t)blockIdx.x * 256 + tid) * 8;
  const uint4 v = *(const uint4*)(ret + i);
  float4 o0, o1;
  o0.x = (__uint_as_float(v.x << 16)          - mn) * sc;
  o0.y = (__uint_as_float(v.x & 0xFFFF0000u)  - mn) * sc;
  o0.z = (__uint_as_float(v.y << 16)          - mn) * sc;
  o0.w = (__uint_as_float(v.y & 0xFFFF0000u)  - mn) * sc;
  o1.x = (__uint_as_float(v.z << 16)          - mn) * sc;
  o1.y = (__uint_as_float(v.z & 0xFFFF0000u)  - mn) * sc;
  o1.z = (__uint_as_float(v.w << 16)          - mn) * sc;
  o1.w = (__uint_as_float(v.w & 0xFFFF0000u)  - mn) * sc;
  *(float4*)(out + i) = o0;
  *(float4*)(out + i + 4) = o1;
}

// ---------- host-side weights (mirrors reference float math) ----------

static void compute_weights(Weights* wt) {
  memset(wt, 0, sizeof(Weights));
  const int   ntap[3]  = {161, 81, 31};
  const int   off[3]   = {0, 161, 242};
  const float sigma[3] = {80.f, 40.f, 15.f};
  for (int s = 0; s < 3; ++s) {
    const int k = ntap[s];
    float g[161];
    float sum = 0.f;
    for (int i = 0; i < k; ++i) {
      float x = (float)i - (float)(k - 1) * 0.5f;
      g[i] = expf(-(x * x) / (2.f * sigma[s] * sigma[s]));
      sum += g[i];
    }
    const float inv = 1.f / sum;
    for (int i = 0; i < k; ++i) wt->w[off[s] + i] = g[i] * inv;
  }
}

// ---------- launch ----------

extern "C" void kernel_launch(void* const* d_in, const int* in_sizes, int n_in,
                              void* d_out, int out_size, void* d_ws, size_t ws_size,
                              hipStream_t stream) {
  const float* img = (const float*)d_in[0];
  float* out = (float*)d_out;
  unsigned* mm = (unsigned*)d_ws;                   // 128 uints (64 slot pairs)
  ushort* frag = (ushort*)((char*)d_ws + 1024);
  ushort* planesT = (ushort*)((char*)d_ws + 32768);               // 144 MB
  ushort* ret = (ushort*)((char*)d_ws + 32768 + (size_t)3 * NP * HW * 2);  // 48 MB

  Weights wt;
  compute_weights(&wt);

  msr_fraginit<<<1, 256, 0, stream>>>(wt, frag, mm);
  msr_hblur3<<<dim3(4, 32, NP), 128, 0, stream>>>(img, planesT, (const bf16x8*)frag);
  msr_vblur3<<<dim3(16, 8, NP), 256, 0, stream>>>(planesT, img, ret, (const bf16x8*)frag, mm);
  msr_norm<<<(unsigned)((size_t)NP * HW / 2048), 256, 0, stream>>>(ret, out, mm);
}

// Round 20
// 235.017 us; speedup vs baseline: 1.0125x; 1.0125x over previous
//
#include <hip/hip_runtime.h>
#include <math.h>
#include <string.h>

#define W 1024
#define H 1024
#define HW (1024*1024)
#define NP 24                 // B*C planes

typedef float  f32x4  __attribute__((ext_vector_type(4)));
typedef short  bf16x8 __attribute__((ext_vector_type(8)));

struct Weights { float w[273]; };   // w80[161]@0, w40[81]@161, w15[31]@242

// LDS pitches (shorts), ≡8 mod 64. Final recombination: r19's pass-2 (k-outer,
// wave-private, barrier-free; 126.4us best) + r18's pass-1 (tx-outer h_round,
// block barrier; best hblur3). Ledger of nulls/regressions: r11 tile-shrink,
// r13 de-staging, r16 persistence, r17 occupancy, r18 barrier-del (p2), r19 k-outer
// (neutral in p2, kept for -8 VGPR). Memory-state invariance proven r18 (L3 replays).
#define P1PIT 456
#define P2P80 328
#define P2P40 264
#define P2P15 200

#define NSLOT 64              // min/max atomic buckets

// planesT blocked layout: elem(sp, y, x) at sp*HW + (y>>5)*32768 + x*32 + (y&31)

// ---------- helpers ----------

__device__ __forceinline__ unsigned fenc(float f) {
  unsigned u = __float_as_uint(f);
  return (u & 0x80000000u) ? ~u : (u | 0x80000000u);
}
__device__ __forceinline__ float fdec(unsigned e) {
  unsigned u = (e & 0x80000000u) ? (e & 0x7fffffffu) : ~e;
  return __uint_as_float(u);
}
__device__ __forceinline__ unsigned bfbits(float f) {   // f32 -> bf16 bits, RNE
  unsigned u = __float_as_uint(f);
  return (u + 0x7fffu + ((u >> 16) & 1u)) >> 16;
}

__device__ __forceinline__ void minmax_reduce4(float lmn, float lmx, unsigned* mm,
                                               float* red, int slot) {
  #pragma unroll
  for (int off = 32; off > 0; off >>= 1) {
    lmn = fminf(lmn, __shfl_xor(lmn, off));
    lmx = fmaxf(lmx, __shfl_xor(lmx, off));
  }
  const int tid = threadIdx.x;
  const int wid = tid >> 6;
  if ((tid & 63) == 0) { red[wid] = lmn; red[4 + wid] = lmx; }
  __syncthreads();
  if (tid == 0) {
    float mn = fminf(fminf(red[0], red[1]), fminf(red[2], red[3]));
    float mx = fmaxf(fmaxf(red[4], red[5]), fmaxf(red[6], red[7]));
    atomicMin(mm + 2 * slot, fenc(mn));
    atomicMax(mm + 2 * slot + 1, fenc(mx));
  }
}

// ---------- init: Toeplitz B-fragment table [3][6][64 lanes] x 8 bf16 ----------

__global__ void msr_fraginit(Weights wt, ushort* __restrict__ frag, unsigned* __restrict__ mm) {
  const int tid = threadIdx.x;
  if (tid < NSLOT) { mm[2 * tid] = 0xFFFFFFFFu; mm[2 * tid + 1] = 0u; }
  const int pads[3] = {80, 40, 15};
  const int woff[3] = {0, 161, 242};
  const int t0s[3]  = {11, 13, 15};
  for (int e = tid; e < 3 * 6 * 64; e += 256) {
    const int s = e / 384;
    const int rem = e - s * 384;
    const int k = rem >> 6;
    const int lane = rem & 63;
    const int pad = pads[s];
    const int d = pad + (t0s[s] + 2 * k) * 16 - 256;
    ushort* dst = frag + e * 8;
    for (int j = 0; j < 8; ++j) {
      const int kk = ((lane >> 4) << 3) + j;
      const int c  = lane & 15;
      const int idx = d + kk - c;
      float v = (idx >= 0 && idx <= 2 * pad) ? wt.w[woff[s] + idx] : 0.f;
      dst[j] = (ushort)bfbits(v);
    }
  }
}

// ---------- pass 1: horizontal blur, 256-wide x-tiles (r18-best: tx-outer, barrier) ----

template<int NK, int C0, int FB>
__device__ __forceinline__ void h_round(const short* __restrict__ lds,
                                        const bf16x8* __restrict__ fragv,
                                        ushort* __restrict__ pT,
                                        int lane, int rowshort, int x16, int yin) {
  bf16x8 fr[NK];
  #pragma unroll
  for (int k = 0; k < NK; ++k) fr[k] = fragv[(FB + k) * 64 + lane];
  #pragma unroll
  for (int tx = 0; tx < 16; ++tx) {
    f32x4 acc = {0.f, 0.f, 0.f, 0.f};
    #pragma unroll
    for (int k = 0; k < NK; ++k) {
      bf16x8 a = *(const bf16x8*)(lds + rowshort + tx * 16 + C0 + 32 * k);
      acc = __builtin_amdgcn_mfma_f32_16x16x32_bf16(a, fr[k], acc, 0, 0, 0);
    }
    const unsigned lo = bfbits(acc[0]) | (bfbits(acc[1]) << 16);
    const unsigned hi = bfbits(acc[2]) | (bfbits(acc[3]) << 16);
    *(uint2*)(pT + (size_t)(x16 + tx * 16) * 32 + yin) = make_uint2(lo, hi);
  }
}

__global__ __launch_bounds__(128, 2) void msr_hblur3(
    const float* __restrict__ img, ushort* __restrict__ planesT,
    const bf16x8* __restrict__ fragv) {
  __shared__ __align__(16) short lds[32 * P1PIT];   // 29184 B -> 5 blocks/CU
  const int tid = threadIdx.x;
  const int orig = blockIdx.x + (blockIdx.y << 2) + (blockIdx.z << 7);
  const int l = (orig & 7) * 384 + (orig >> 3);     // bijective (3072 = 8*384)
  const int bx = l & 3;            // x-tile (256 wide, halo axis)
  const int by = (l >> 2) & 31;    // y-strip (32 tall)
  const int bp = l >> 7;           // plane
  const int x0 = bx * 256, y0 = by * 32;
  const float* sp = img + (size_t)bp * HW;
  const int row = tid >> 2, c4 = tid & 3;
  const bool interior = (bx == 1 || bx == 2);
  #pragma unroll
  for (int it = 0; it < 28; ++it) {
    const int ccpx = 4 * c4 + 16 * it;
    const int gx0 = x0 - 96 + ccpx;
    unsigned lo, hi;
    if (interior || (gx0 >= 0 && gx0 + 4 <= W)) {
      const float4 v = *(const float4*)(sp + (size_t)(y0 + row) * W + gx0);
      lo = bfbits(v.x) | (bfbits(v.y) << 16);
      hi = bfbits(v.z) | (bfbits(v.w) << 16);
    } else {
      unsigned us[4];
      #pragma unroll
      for (int j = 0; j < 4; ++j) {
        int gx = gx0 + j;
        gx = gx < 0 ? -gx : (gx >= W ? 2 * W - 2 - gx : gx);
        us[j] = bfbits(sp[(size_t)(y0 + row) * W + gx]);
      }
      lo = us[0] | (us[1] << 16); hi = us[2] | (us[3] << 16);
    }
    *(uint2*)(lds + row * P1PIT + ccpx) = make_uint2(lo, hi);
  }
  __syncthreads();

  const int lane = tid & 63;
  const int wrow = (tid >> 6) * 16;
  const int q = lane >> 4;
  const int rowshort = (wrow + (lane & 15)) * P1PIT + q * 8;
  const int x16 = x0 + (lane & 15);
  const int yin = wrow + q * 4;
  const size_t sb = (size_t)by * 32768;

  h_round<6, 16, 0>(lds, fragv, planesT + (size_t)(0 * NP + bp) * HW + sb, lane, rowshort, x16, yin);
  h_round<4, 48, 6>(lds, fragv, planesT + (size_t)(1 * NP + bp) * HW + sb, lane, rowshort, x16, yin);
  h_round<2, 80, 12>(lds, fragv, planesT + (size_t)(2 * NP + bp) * HW + sb, lane, rowshort, x16, yin);
}

// ---------- pass 2 (r19-best): wave-private staging, no barriers, k-outer conv ----------

template<int NCH, int WD>
__device__ __forceinline__ void p2_prefetch(const ushort* __restrict__ pTs, int xrow,
                                            int ystart, int c4, uint4 (&pre)[10]) {
  #pragma unroll
  for (int i = 0; i < NCH; ++i) {
    const int ccpx = 8 * c4 + 32 * i;
    if (ccpx < WD) {
      const int gy = ystart + ccpx;                // ≡0 mod 8 -> never straddles a strip
      if (gy >= 0 && gy + 8 <= H) {
        pre[i] = *(const uint4*)(pTs + (size_t)(gy >> 5) * 32768 + (size_t)xrow * 32 + (gy & 31));
      } else {
        union { ushort u[8]; uint4 v; } t;
        #pragma unroll
        for (int j = 0; j < 8; ++j) {
          int g = gy + j;
          g = g < 0 ? -g : (g >= H ? 2 * H - 2 - g : g);
          t.u[j] = pTs[(size_t)(g >> 5) * 32768 + (size_t)xrow * 32 + (g & 31)];
        }
        pre[i] = t.v;
      }
    }
  }
}

template<int NCH, int WD, int PIT>
__device__ __forceinline__ void p2_wlds(short* __restrict__ lds, int srow, int c4,
                                        const uint4 (&pre)[10]) {
  #pragma unroll
  for (int i = 0; i < NCH; ++i) {
    const int ccpx = 8 * c4 + 32 * i;
    if (ccpx < WD) *(uint4*)(lds + srow * PIT + ccpx) = pre[i];
  }
}

template<int NK, int PIT, int FB, bool FIRST>
__device__ __forceinline__ void p2_convprod(const short* __restrict__ lds,
                                            const bf16x8* __restrict__ fragv,
                                            int lane, int wrow, float* prod) {
  const int rowshort = (wrow + (lane & 15)) * PIT + (lane >> 4) * 8;
  bf16x8 fr[NK];
  #pragma unroll
  for (int k = 0; k < NK; ++k) fr[k] = fragv[(FB + k) * 64 + lane];
  f32x4 acc[8];
  #pragma unroll
  for (int tx = 0; tx < 8; ++tx) acc[tx] = (f32x4){0.f, 0.f, 0.f, 0.f};
  #pragma unroll
  for (int k = 0; k < NK; ++k) {          // k OUTER: 8 independent MFMA chains
    #pragma unroll
    for (int tx = 0; tx < 8; ++tx) {
      bf16x8 a = *(const bf16x8*)(lds + rowshort + tx * 16 + 32 * k);
      acc[tx] = __builtin_amdgcn_mfma_f32_16x16x32_bf16(a, fr[k], acc[tx], 0, 0, 0);
    }
  }
  #pragma unroll
  for (int tx = 0; tx < 8; ++tx) {
    #pragma unroll
    for (int r = 0; r < 4; ++r) {
      const float v = acc[tx][r] + 2e-6f;
      if (FIRST) prod[tx * 4 + r] = v;
      else       prod[tx * 4 + r] *= v;
    }
  }
}

__global__ __launch_bounds__(256) __attribute__((amdgpu_waves_per_eu(2, 3)))
void msr_vblur3(
    const ushort* __restrict__ planesT, const float* __restrict__ img,
    ushort* __restrict__ ret, const bf16x8* __restrict__ fragv, unsigned* __restrict__ mm) {
  __shared__ __align__(16) short lds[64 * P2P80];   // 41984 B
  __shared__ float red[8];
  const int tid = threadIdx.x;
  const int orig = blockIdx.x + (blockIdx.y << 4) + (blockIdx.z << 7);
  const int l = (orig & 7) * 384 + (orig >> 3);     // bijective (3072 = 8*384)
  const int byt = l & 7;           // y-tile (128 tall, halo axis -> same XCD)
  const int bxt = (l >> 3) & 15;   // x-tile (64 wide)
  const int bp = l >> 7;
  const int x0 = bxt * 64, y0 = byt * 128;
  const int lane = tid & 63;
  const int wrow = (tid >> 6) * 16;
  const int srow = wrow + (lane >> 2);    // wave-private staging row (16 per wave)
  const int c4 = lane & 3;
  const int q = lane >> 4;
  const int xb = x0 + wrow + 4 * q;       // C rows = x (4 consecutive per lane)
  const int ycb = y0 + (lane & 15);       // C cols = y (+ tx*16)

  const ushort* pT0 = planesT + (size_t)(0 * NP + bp) * HW;
  const ushort* pT1 = planesT + (size_t)(1 * NP + bp) * HW;
  const ushort* pT2 = planesT + (size_t)(2 * NP + bp) * HW;

  uint4 pre[10];
  p2_prefetch<10, 304>(pT0, x0 + srow, y0 - 80, c4, pre);  // sigma80 window in flight

  // accL init from img (VALU stretch overlaps prefetch)
  float accL[32];
  const float* ip = img + (size_t)bp * HW;
  #pragma unroll
  for (int tx = 0; tx < 8; ++tx) {
    const float4 v = *(const float4*)(ip + (size_t)(ycb + tx * 16) * W + xb);
    accL[tx * 4 + 0] = 3.f * __logf(v.x + 1e-6f);
    accL[tx * 4 + 1] = 3.f * __logf(v.y + 1e-6f);
    accL[tx * 4 + 2] = 3.f * __logf(v.z + 1e-6f);
    accL[tx * 4 + 3] = 3.f * __logf(v.w + 1e-6f);
  }

  float prod[32];
  // round sigma80 (no barriers: wave-private stripes)
  p2_wlds<10, 304, P2P80>(lds, srow, c4, pre);
  p2_prefetch<8, 240>(pT1, x0 + srow, y0 - 48, c4, pre);   // next round in flight
  p2_convprod<6, P2P80, 0, true>(lds, fragv, lane, wrow, prod);
  // round sigma40
  p2_wlds<8, 240, P2P40>(lds, srow, c4, pre);
  p2_prefetch<6, 176>(pT2, x0 + srow, y0 - 16, c4, pre);
  p2_convprod<4, P2P40, 6, false>(lds, fragv, lane, wrow, prod);
  // round sigma15
  p2_wlds<6, 176, P2P15>(lds, srow, c4, pre);
  p2_convprod<2, P2P15, 12, false>(lds, fragv, lane, wrow, prod);

  ushort* rp = ret + (size_t)bp * HW;
  float lmn = 3.4e38f, lmx = -3.4e38f;
  #pragma unroll
  for (int tx = 0; tx < 8; ++tx) {
    #pragma unroll
    for (int r = 0; r < 4; ++r) {
      accL[tx * 4 + r] -= __logf(prod[tx * 4 + r]);
      lmn = fminf(lmn, accL[tx * 4 + r]);
      lmx = fmaxf(lmx, accL[tx * 4 + r]);
    }
    const unsigned lo = bfbits(accL[tx * 4 + 0]) | (bfbits(accL[tx * 4 + 1]) << 16);
    const unsigned hi = bfbits(accL[tx * 4 + 2]) | (bfbits(accL[tx * 4 + 3]) << 16);
    *(uint2*)(rp + (size_t)(ycb + tx * 16) * W + xb) = make_uint2(lo, hi);
  }
  minmax_reduce4(lmn, lmx, mm, red, orig & (NSLOT - 1));
}

// ---------- normalize: self-reduces slots; reads bf16 retinex, writes f32 out ----------

__global__ __launch_bounds__(256) void msr_norm(const ushort* __restrict__ ret,
                                                float* __restrict__ out,
                                                const unsigned* __restrict__ mm) {
  __shared__ float smn, ssc;
  const int tid = threadIdx.x;
  if (tid < 64) {
    unsigned e = mm[2 * tid];
    unsigned f = mm[2 * tid + 1];
    #pragma unroll
    for (int off = 32; off > 0; off >>= 1) {
      unsigned eo = (unsigned)__shfl_xor((int)e, off);
      unsigned fo = (unsigned)__shfl_xor((int)f, off);
      e = eo < e ? eo : e;
      f = fo > f ? fo : f;
    }
    if (tid == 0) {
      const float mn = fdec(e), mx = fdec(f);
      smn = mn;
      ssc = 255.f / (mx - mn);
    }
  }
  __syncthreads();
  const float mn = smn, sc = ssc;
  const size_t i = ((size_t)blockIdx.x * 256 + tid) * 8;
  const uint4 v = *(const uint4*)(ret + i);
  float4 o0, o1;
  o0.x = (__uint_as_float(v.x << 16)          - mn) * sc;
  o0.y = (__uint_as_float(v.x & 0xFFFF0000u)  - mn) * sc;
  o0.z = (__uint_as_float(v.y << 16)          - mn) * sc;
  o0.w = (__uint_as_float(v.y & 0xFFFF0000u)  - mn) * sc;
  o1.x = (__uint_as_float(v.z << 16)          - mn) * sc;
  o1.y = (__uint_as_float(v.z & 0xFFFF0000u)  - mn) * sc;
  o1.z = (__uint_as_float(v.w << 16)          - mn) * sc;
  o1.w = (__uint_as_float(v.w & 0xFFFF0000u)  - mn) * sc;
  *(float4*)(out + i) = o0;
  *(float4*)(out + i + 4) = o1;
}

// ---------- host-side weights (mirrors reference float math) ----------

static void compute_weights(Weights* wt) {
  memset(wt, 0, sizeof(Weights));
  const int   ntap[3]  = {161, 81, 31};
  const int   off[3]   = {0, 161, 242};
  const float sigma[3] = {80.f, 40.f, 15.f};
  for (int s = 0; s < 3; ++s) {
    const int k = ntap[s];
    float g[161];
    float sum = 0.f;
    for (int i = 0; i < k; ++i) {
      float x = (float)i - (float)(k - 1) * 0.5f;
      g[i] = expf(-(x * x) / (2.f * sigma[s] * sigma[s]));
      sum += g[i];
    }
    const float inv = 1.f / sum;
    for (int i = 0; i < k; ++i) wt->w[off[s] + i] = g[i] * inv;
  }
}

// ---------- launch ----------

extern "C" void kernel_launch(void* const* d_in, const int* in_sizes, int n_in,
                              void* d_out, int out_size, void* d_ws, size_t ws_size,
                              hipStream_t stream) {
  const float* img = (const float*)d_in[0];
  float* out = (float*)d_out;
  unsigned* mm = (unsigned*)d_ws;                   // 128 uints (64 slot pairs)
  ushort* frag = (ushort*)((char*)d_ws + 1024);
  ushort* planesT = (ushort*)((char*)d_ws + 32768);               // 144 MB
  ushort* ret = (ushort*)((char*)d_ws + 32768 + (size_t)3 * NP * HW * 2);  // 48 MB

  Weights wt;
  compute_weights(&wt);

  msr_fraginit<<<1, 256, 0, stream>>>(wt, frag, mm);
  msr_hblur3<<<dim3(4, 32, NP), 128, 0, stream>>>(img, planesT, (const bf16x8*)frag);
  msr_vblur3<<<dim3(16, 8, NP), 256, 0, stream>>>(planesT, img, ret, (const bf16x8*)frag, mm);
  msr_norm<<<(unsigned)((size_t)NP * HW / 2048), 256, 0, stream>>>(ret, out, mm);
}